// Round 2
// baseline (103514.453 us; speedup 1.0000x reference)
//
#include <hip/hip_runtime.h>

// ============================================================================
// Persistent pipelined LSTM-with-projection, fp32, MI355X (gfx950).
//
// grid = 256 WGs = 4 layers x 64 cell-slices (16 cells each), 1 WG/CU
// (LDS-bound). Gate weights live in LDS for the whole kernel (k-major,
// row^(4*(k&1)) swizzle -> <=2-way bank conflicts). Gate GEMM: 8x8 register
// tile per thread, k split 4-ways across lane quads (lane = 4*c16 + ksub),
// partials combined with 2 DPP quad-permute adds (VALU-only, no barrier).
// h history is an 8-slot ring [slot][p][b] (ws ~18 MB); layers pipeline via
// per-(layer,WG) epoch flags + agent-scope fences; back-pressure waits keep
// the ring safe. blockIdx remapped so each layer owns an XCD pair (L2
// locality for the cross-WG projection reduce).
// ============================================================================

#define B_    64
#define T_    1024
#define P_    256
#define H_    1024
#define L_    4
#define G4_   4096
#define NTHR  256
#define WWIN  8                     // h ring slots (power of two)
#define HSLOT (P_ * B_)             // 16384 floats per slot, layout [p][b]

#define LDS_W     (512 * 64)        // 32768 floats, k-major, swizzled rows
#define LDS_XH    4096              // 2 x (32k x 64b) staging; reused as WRS
#define LDS_ACT   1024              // act [16 cells][64 b]
#define LDS_BIAS  64
#define LDS_FLOATS (LDS_W + LDS_XH + LDS_ACT + LDS_BIAS)
#define LDS_BYTES  (LDS_FLOATS * 4) // 151808 B

#define PART_FLOATS ((size_t)L_ * 64 * P_ * B_)        // 16 MB
#define HBUF_FLOATS ((size_t)L_ * WWIN * HSLOT)        // 2 MB

struct alignas(16) F4 { float f[4]; };

__device__ __forceinline__ float fsig(float x) {
  float e = __expf(-x);                       // saturation-safe
  return __builtin_amdgcn_rcpf(1.0f + e);
}
__device__ __forceinline__ float ftanh(float x) {
  float ax = fabsf(x);
  float e  = __expf(-2.0f * ax);              // in (0,1] -> no overflow/NaN
  float r  = (1.0f - e) * __builtin_amdgcn_rcpf(1.0f + e);
  return copysignf(r, x);
}
// sum over lane quads {4q..4q+3}: butterfly xor1 then xor2 (quad_perm DPP)
__device__ __forceinline__ float qsum(float v) {
  v += __int_as_float(__builtin_amdgcn_update_dpp(
        0, __float_as_int(v), 0xB1, 0xF, 0xF, false)); // [1,0,3,2]
  v += __int_as_float(__builtin_amdgcn_update_dpp(
        0, __float_as_int(v), 0x4E, 0xF, 0xF, false)); // [2,3,0,1]
  return v;
}
__device__ __forceinline__ void wait_flags(int* f, int lane, int target) {
  while (true) {
    int v = __hip_atomic_load(&f[lane], __ATOMIC_RELAXED, __HIP_MEMORY_SCOPE_AGENT);
    if (__ballot(v < target) == 0ull) break;
    __builtin_amdgcn_s_sleep(2);
  }
}

extern "C" __global__ void __launch_bounds__(NTHR, 1)
lstm_persistent(const float* __restrict__ y,
                const float* __restrict__ Wih,
                const float* __restrict__ Whh,
                const float* __restrict__ bih,
                const float* __restrict__ bhh,
                const float* __restrict__ Whr,
                const int*   __restrict__ mslp,
                float*       __restrict__ out,
                float*       __restrict__ hbuf,
                float*       __restrict__ part,
                int*         __restrict__ hflag,
                int*         __restrict__ pflag)
{
  extern __shared__ float lds[];
  float* Ws   = lds;
  float* XH   = lds + LDS_W;
  float* ACT  = XH + LDS_XH;
  float* BIAS = ACT + LDS_ACT;

  // XCD-pair remap: layer l on XCDs {2l,2l+1} if blocks round-robin bid%8.
  const int bid = blockIdx.x;
  const int l   = (bid & 7) >> 1;
  const int w   = ((bid & 1)) + 2 * (bid >> 3);   // 0..63, bijective
  const int J0  = w * 16;
  const int tid  = threadIdx.x;
  const int lane = tid & 63;
  const int msl  = mslp[0];

  // ---- one-time: gate-weight slice (k-major, swizzled) + bias into LDS ----
  {
    const float* wih_l = Wih + (size_t)l * G4_ * P_;
    const float* whh_l = Whh + (size_t)l * G4_ * P_;
    for (int it = 0; it < 32; ++it) {
      int idx4 = tid + NTHR * it;            // 8192 F4 total
      int r    = idx4 >> 7;                  // 0..63, r = 4*cell + gate
      int k4   = (idx4 & 127) << 2;          // 0..508
      int g = r & 3, j = r >> 2;
      int grow = g * H_ + J0 + j;            // torch gate order i,f,g,o
      F4 v;
      if (k4 < 256) v = *(const F4*)&wih_l[(size_t)grow * P_ + k4];
      else          v = *(const F4*)&whh_l[(size_t)grow * P_ + (k4 - 256)];
#pragma unroll
      for (int i = 0; i < 4; ++i)
        Ws[(size_t)(k4 + i) * 64 + (r ^ (4 * (i & 1)))] = v.f[i];
    }
    if (tid < 64) {
      int g = tid & 3, j = tid >> 2;
      int grow = g * H_ + J0 + j;
      BIAS[tid] = bih[l * G4_ + grow] + bhh[l * G4_ + grow];
    }
  }
  __syncthreads();

  // ---- thread mappings ----------------------------------------------------
  const int w4   = tid >> 6;            // wave 0..3
  const int c16  = lane >> 2;           // 0..15
  const int ksub = lane & 3;            // k-split lane within quad
  const int lr   = (w4 << 1) | (c16 >> 3);   // 0..7 -> rows 8lr..8lr+7
  const int lb   = c16 & 7;                  // 0..7 -> b 8lb..8lb+7
  const int swz  = 4 * (ksub & 1);           // W row swizzle (kl&1 == ksub&1)
  // staging (transpose path, layer 0 input y):
  const int sb0 = tid >> 3, skq = tid & 7, skl = skq << 2;
  // staging (fast path, h ring [p][b]):
  const int kidx = tid >> 3, bq = tid & 7;
  // projection:
  const int tb2 = tid & 15, tp = tid >> 4;
  // reduce:
  const int rpo = tid >> 6, rb = tid & 63;

  float* hsrc = hbuf + (size_t)l * (WWIN * HSLOT);
  const float* hprv = (l > 0) ? (hbuf + (size_t)(l - 1) * (WWIN * HSLOT)) : hbuf;

  // bias regs for own rows
  float biasr[8];
#pragma unroll
  for (int i = 0; i < 8; ++i) biasr[i] = BIAS[8 * lr + i];

  // Whr fragment (constant): rows p = tid, cells J0..J0+15
  const float* wl = Whr + ((size_t)l * P_ + tid) * H_ + J0;
  F4 q0 = *(const F4*)&wl[0];
  F4 q1 = *(const F4*)&wl[4];
  F4 q2 = *(const F4*)&wl[8];
  F4 q3 = *(const F4*)&wl[12];

  float cst[2][2] = {{0.f, 0.f}, {0.f, 0.f}};  // c for (cell 2lr+m, b 8lb+2ksub+n)

  for (int t = 0; t < T_; ++t) {
    if (l > 0) wait_flags(hflag + (l - 1) * 64, lane, t);
    if (t > 0) wait_flags(hflag + l * 64, lane, t - 1);
    __threadfence();                    // acquire: see remote h/part writes

    const int nch = (t == 0) ? 8 : 16;  // t==0: h=0, skip Whh half

    float acc[8][8];
#pragma unroll
    for (int i = 0; i < 8; ++i)
#pragma unroll
      for (int jx = 0; jx < 8; ++jx) acc[i][jx] = 0.f;

    // stage one 32k x 64b chunk into dst, layout X[k][ b ^ (k&28) ^ 4(k&1) ]
    auto stage = [&](int cc, float* dst) {
      const int koff = (cc & 7) << 5;
      if (l == 0 && cc < 8) {           // y is [b][T][P]: transpose path
        F4 ra  = *(const F4*)(y + ((size_t)sb0 * T_ + t) * P_ + koff + skl);
        F4 rb4 = *(const F4*)(y + ((size_t)(sb0 + 32) * T_ + t) * P_ + koff + skl);
#pragma unroll
        for (int i2 = 0; i2 < 4; ++i2) {
          const int sw = (skq << 2) ^ (4 * (i2 & 1));
          dst[(skl + i2) * 64 + (sb0 ^ sw)]        = ra.f[i2];
          dst[(skl + i2) * 64 + ((sb0 + 32) ^ sw)] = rb4.f[i2];
        }
      } else {                          // h ring is [slot][p][b]: direct F4
        const float* src = (cc < 8) ? hprv + (size_t)(t & (WWIN - 1)) * HSLOT
                                    : hsrc + (size_t)((t - 1) & (WWIN - 1)) * HSLOT;
        const float* pb = src + (size_t)(koff + kidx) * 64 + 4 * bq;
        F4 a = *(const F4*)(pb);
        F4 b = *(const F4*)(pb + 32);
        const int sx = (kidx & 28) ^ (4 * (kidx & 1));
        *(F4*)&dst[kidx * 64 + ((4 * bq) ^ sx)]      = a;
        *(F4*)&dst[kidx * 64 + ((4 * bq + 32) ^ sx)] = b;
      }
    };

    stage(0, XH);
    __syncthreads();

    // ---- gate GEMM: 64r x 64b x 512k, double-buffered 32k chunks ----------
    for (int cc = 0; cc < nch; ++cc) {
      if (cc + 1 < nch) stage(cc + 1, XH + (((cc + 1) & 1) << 11));
      const float* buf = XH + ((cc & 1) << 11);
      const int kb = cc << 5;
#pragma unroll
      for (int jj = 0; jj < 8; ++jj) {
        const int kl = 4 * jj + ksub;                   // this lane's k
        const float* wrow = Ws + (size_t)(kb + kl) * 64;
        F4 wlo = *(const F4*)&wrow[(8 * lr) ^ swz];     // rows 8lr..+3
        F4 whi = *(const F4*)&wrow[(8 * lr + 4) ^ swz]; // rows 8lr+4..+7
        const int sx = (4 * jj) ^ swz;                  // kl&28 = 4*jj
        const float* xrow = buf + kl * 64;
        F4 xlo = *(const F4*)&xrow[(8 * lb) ^ sx];      // b 8lb..+3
        F4 xhi = *(const F4*)&xrow[(8 * lb + 4) ^ sx];  // b 8lb+4..+7
#pragma unroll
        for (int i = 0; i < 4; ++i)
#pragma unroll
          for (int jx = 0; jx < 4; ++jx) {
            acc[i][jx]         = fmaf(wlo.f[i], xlo.f[jx], acc[i][jx]);
            acc[i][jx + 4]     = fmaf(wlo.f[i], xhi.f[jx], acc[i][jx + 4]);
            acc[i + 4][jx]     = fmaf(whi.f[i], xlo.f[jx], acc[i + 4][jx]);
            acc[i + 4][jx + 4] = fmaf(whi.f[i], xhi.f[jx], acc[i + 4][jx + 4]);
          }
      }
      __syncthreads();
    }

    // ---- combine k-split partials across lane quads (VALU-only) -----------
#pragma unroll
    for (int i = 0; i < 8; ++i)
#pragma unroll
      for (int jx = 0; jx < 8; ++jx) acc[i][jx] = qsum(acc[i][jx]);

    // ---- activations + cell update; own cols are 2ksub,2ksub+1 ------------
#pragma unroll
    for (int m = 0; m < 2; ++m)
#pragma unroll
      for (int n = 0; n < 2; ++n) {
        // 2-level mux (compile-time register indices only)
#define MUX(I) ((ksub & 2) ? ((ksub & 1) ? acc[I][6 + n] : acc[I][4 + n])  \
                           : ((ksub & 1) ? acc[I][2 + n] : acc[I][0 + n]))
        float vi = MUX(4 * m + 0) + biasr[4 * m + 0];
        float vf = MUX(4 * m + 1) + biasr[4 * m + 1];
        float vg = MUX(4 * m + 2) + biasr[4 * m + 2];
        float vo = MUX(4 * m + 3) + biasr[4 * m + 3];
#undef MUX
        float ig = fsig(vi), fg = fsig(vf), gg = ftanh(vg), og = fsig(vo);
        float cn = fmaf(fg, cst[m][n], ig * gg);
        cst[m][n] = cn;
        ACT[(2 * lr + m) * 64 + (8 * lb + 2 * ksub + n)] = og * ftanh(cn);
      }

    // stage Whr slice (from regs) into XH region as WRS[16 cells][256 p]
    float* WRS = XH;
#pragma unroll
    for (int jj = 0; jj < 4; ++jj) WRS[jj * 256 + tid]        = q0.f[jj];
#pragma unroll
    for (int jj = 0; jj < 4; ++jj) WRS[(4 + jj) * 256 + tid]  = q1.f[jj];
#pragma unroll
    for (int jj = 0; jj < 4; ++jj) WRS[(8 + jj) * 256 + tid]  = q2.f[jj];
#pragma unroll
    for (int jj = 0; jj < 4; ++jj) WRS[(12 + jj) * 256 + tid] = q3.f[jj];
    __syncthreads();

    // ---- partial projection: own 16 cells x 256p x 64b --------------------
    float pa[4][16];
#pragma unroll
    for (int a = 0; a < 4; ++a)
#pragma unroll
      for (int b2 = 0; b2 < 16; ++b2) pa[a][b2] = 0.f;
#pragma unroll
    for (int j = 0; j < 16; ++j) {
      F4 af = *(const F4*)&ACT[j * 64 + 4 * tb2];
#pragma unroll
      for (int c = 0; c < 4; ++c) {
        const int c2 = (c + tp) & 3;               // stagger p-chunks
        F4 wf = *(const F4*)&WRS[j * 256 + 16 * tp + 4 * c2];
#pragma unroll
        for (int u = 0; u < 4; ++u) {
          pa[0][4 * c + u] = fmaf(af.f[0], wf.f[u], pa[0][4 * c + u]);
          pa[1][4 * c + u] = fmaf(af.f[1], wf.f[u], pa[1][4 * c + u]);
          pa[2][4 * c + u] = fmaf(af.f[2], wf.f[u], pa[2][4 * c + u]);
          pa[3][4 * c + u] = fmaf(af.f[3], wf.f[u], pa[3][4 * c + u]);
        }
      }
    }
    {
      float* pw = part + (((size_t)l * 64 + w) * P_) * B_;   // [p][b]
#pragma unroll
      for (int c = 0; c < 4; ++c) {
        const int c2 = (c + tp) & 3;
        const int pbase = 16 * tp + 4 * c2;
#pragma unroll
        for (int u = 0; u < 4; ++u) {
          F4 vv;
          vv.f[0] = pa[0][4 * c + u]; vv.f[1] = pa[1][4 * c + u];
          vv.f[2] = pa[2][4 * c + u]; vv.f[3] = pa[3][4 * c + u];
          *(F4*)&pw[(size_t)(pbase + u) * B_ + 4 * tb2] = vv;
        }
      }
    }
    __syncthreads();
    if (tid == 0) {
      __threadfence();   // release partials device-wide
      __hip_atomic_store(&pflag[l * 64 + w], t, __ATOMIC_RELAXED, __HIP_MEMORY_SCOPE_AGENT);
    }

    // ---- reduce 64 partials for own 4-wide p slice, emit h ----------------
    wait_flags(pflag + l * 64, lane, t);
    if (l < 3) wait_flags(hflag + (l + 1) * 64, lane, t - WWIN);  // ring back-pressure
    __threadfence();     // acquire partials
    {
      const int p = 4 * w + rpo;
      const float* pb = part + (size_t)l * 64 * P_ * B_ + (size_t)p * B_ + rb;
      float s = 0.f;
#pragma unroll
      for (int wp = 0; wp < 64; ++wp) s += pb[(size_t)wp * P_ * B_];
      hsrc[(size_t)(t & (WWIN - 1)) * HSLOT + p * 64 + rb] = s;   // [slot][p][b]
      if (l == 3 && t >= msl)
        out[((size_t)rb * (T_ - msl) + (t - msl)) * P_ + p] = s;
    }
    __syncthreads();
    if (tid == 0) {
      __threadfence();   // release h
      __hip_atomic_store(&hflag[l * 64 + w], t, __ATOMIC_RELAXED, __HIP_MEMORY_SCOPE_AGENT);
    }
  }
}

extern "C" void kernel_launch(void* const* d_in, const int* in_sizes, int n_in,
                              void* d_out, int out_size, void* d_ws, size_t ws_size,
                              hipStream_t stream) {
  const float* y   = (const float*)d_in[0];
  const float* Wih = (const float*)d_in[1];
  const float* Whh = (const float*)d_in[2];
  const float* bih = (const float*)d_in[3];
  const float* bhh = (const float*)d_in[4];
  const float* Whr = (const float*)d_in[5];
  const int*   msl = (const int*)d_in[6];
  float* out = (float*)d_out;

  // ws: [flags 4KB][partials 16MB][h ring 2MB]  (~18 MB total)
  char*  ws    = (char*)d_ws;
  int*   flags = (int*)ws;
  float* part  = (float*)(ws + 4096);
  float* hbuf  = (float*)(ws + 4096 + PART_FLOATS * sizeof(float));

  hipMemsetAsync(flags, 0xFF, 4096, stream);   // epoch counters start at -1

  hipFuncSetAttribute(reinterpret_cast<const void*>(&lstm_persistent),
                      hipFuncAttributeMaxDynamicSharedMemorySize, LDS_BYTES);

  lstm_persistent<<<dim3(L_ * 64), dim3(NTHR), LDS_BYTES, stream>>>(
      y, Wih, Whh, bih, bhh, Whr, msl, out,
      hbuf, part, flags /*hflag*/, flags + 256 /*pflag*/);
}